// Round 7
// baseline (184.115 us; speedup 1.0000x reference)
//
#include <hip/hip_runtime.h>
#include <stdint.h>
#include <stddef.h>

typedef short bfrag __attribute__((ext_vector_type(8)));
typedef float f32x4 __attribute__((ext_vector_type(4)));
typedef float f32x4u __attribute__((ext_vector_type(4), aligned(4)));  // rows are only 4B-aligned

#define NSEQ 7
// feats packed in MFMA A-fragment order: [btile(1024)][step(18)][lane(64)][j(8)] bf16
// value = feat[btile*16 + (lane&15)][k], k = step*32 + (lane>>4)*8 + j

__constant__ int c_ks[5] = {1, 3, 5, 7, 9};

// per-ksize active MFMA K-steps (B is exactly zero outside): s in [lo, lo+n)
#define SLO0 3
#define SLO1 2
#define SLO2 1
#define SLO3 0
#define SLO4 0
#define SN0 1
#define SN1 3
#define SN2 5
#define SN3 6
#define SN4 7

// LDS layout (halfwords): staging [32][SHW] bf16 (SHW padded to ==24 mod 64);
// max SHW = 664 (L=18) -> 21248 hw staging. pmax int[32][84] above: stride 84
// (not 80) so the 4-quad atomicMax merge is a free 2-way bank split instead of
// 4-way (336*q = 16q mod 32 spreads quads; 320*q = 0 collided them — r4's 3.6M
// SQ_LDS_BANK_CONFLICT was the atomics). Total 53248 B -> 3 blocks/CU (159744).
#define STAGE_MAX_HW 21248
#define PMAX_STRIDE 84
#define XL_HW (STAGE_MAX_HW + 32 * PMAX_STRIDE * 2)   // 26624 hw = 53248 B

static __device__ __forceinline__ unsigned short f2bf(float f) {
  unsigned int u = __float_as_uint(f);
  u += 0x7FFFu + ((u >> 16) & 1u);   // RNE
  return (unsigned short)(u >> 16);
}

// ---------------- prep: pack conv weights + lin1 into B-fragment layout ----------
struct PrepArgs {
  const float* Wk[5];
  const float* lin1_w;
  bfrag* Wpack;
  bfrag* lin1pack;
};

__global__ __launch_bounds__(256) void prep_kernel(PrepArgs a) {
  int tid = blockIdx.x * 256 + threadIdx.x;
  const int NW = NSEQ * 5 * 7 * 64;
  if (tid < NW) {
    int lane = tid & 63, rest = tid >> 6;
    int step = rest % 7, nt = (rest / 7) % 5, seq = rest / 35;
    int quad = lane >> 4, f = lane & 15;
    int ks = c_ks[nt], off = (9 - ks) >> 1;
    const float* W = a.Wk[nt];
    bfrag s;
#pragma unroll
    for (int j = 0; j < 8; ++j) {
      int k = step * 32 + quad * 8 + j;
      int t = k / 24, c = k % 24;
      int tap = t - off;
      float val = 0.f;
      if (c < 20 && tap >= 0 && tap < ks)
        val = W[((seq * 16 + f) * 20 + c) * ks + tap] * 0.2f;  // fold /5
      s[j] = (short)f2bf(val);
    }
    a.Wpack[tid] = s;
  } else if (tid < NW + 4 * 18 * 64) {
    int t2 = tid - NW;
    int lane = t2 & 63, rest = t2 >> 6;
    int step = rest % 18, nt = rest / 18;
    int quad = lane >> 4, col = lane & 15;
    int n = nt * 16 + col;
    bfrag s;
#pragma unroll
    for (int j = 0; j < 8; ++j) {
      int k = step * 32 + quad * 8 + j;
      float val = (k < 560) ? a.lin1_w[n * 560 + k] : 0.f;  // zero rows k>=560 make feats pad inert
      s[j] = (short)f2bf(val);
    }
    a.lin1pack[t2] = s;
  }
}

// ---------------- conv+relu+gmax: sample-tile MFMA, register max over positions ----
struct ConvArgs {
  const float* x[NSEQ];
  const bfrag* Wpack;
  unsigned short* feats;   // packed A-frag layout, see top
};

template <int SLO, int SN>
static __device__ __forceinline__ void mfma_group(f32x4& acc, int s, const bfrag& Af,
                                                  const bfrag* BfBase) {
  if (s >= SLO && s < SLO + SN)
    acc = __builtin_amdgcn_mfma_f32_16x16x32_bf16(Af, BfBase[s - SLO], acc, 0, 0, 0);
}

// One 16-sample MFMA tile over all 5 filter groups. arow = A base (includes quad*8).
static __device__ __forceinline__ void tile_mfma(const unsigned short* arow, const bfrag* Bf,
                                                 f32x4 acc[5]) {
#pragma unroll
  for (int s = 0; s < 7; ++s) {
    bfrag Af = *(const bfrag*)(arow + s * 32);
    mfma_group<SLO0, SN0>(acc[0], s, Af, Bf + 0);
    mfma_group<SLO1, SN1>(acc[1], s, Af, Bf + 1);
    mfma_group<SLO2, SN2>(acc[2], s, Af, Bf + 4);
    mfma_group<SLO3, SN3>(acc[3], s, Af, Bf + 9);
    acc[4] = __builtin_amdgcn_mfma_f32_16x16x32_bf16(Af, Bf[15 + s], acc[4], 0, 0, 0);
  }
}

// Block = 64 samples = 2 chunks of 32 (2 M-tiles of 16 each). Bf preload and the
// full-slab zero (pads/halo) are hoisted and amortized over both chunks — halves
// the per-block Wpack L2 traffic (was 88 KB x 3584 blocks) and zero-phase cost.
// Per chunk: {zero pmax + stage payload} -> bar -> compute (register fmax over
// positions, one 20-op atomicMax merge per wave per tile) -> bar -> store -> bar.
// NO explicit load/compute pipelining: r6 measured it at -13% (compiler + 3
// resident blocks/CU already overlap; sched_barrier pinning defeats the scheduler).
// Live set: Bf 88 + acc 20 + vmax 20 + addr ~12 -> needs 3-waves/EU VGPR budget;
// (256,4)=128 caused scratch spills in r2.
template <int L>
__device__ __forceinline__ void conv_body(unsigned short* xl, const ConvArgs& a,
                                          const int seq, const int b0) {
  constexpr int Pv = L + 9;                 // 4 leading pad + L + 5 trailing pad
  constexpr int SHW0 = Pv * 24;
  constexpr int SHW = SHW0 + ((24 - (SHW0 & 63)) & 63);   // == 24 mod 64 halfwords
  constexpr int STAGE_HW = 32 * SHW;
  constexpr int NC = (L + 3) / 4;           // overlapping float4 chunks per row
  constexpr int NJ = 320 * NC;              // jobs per 32-sample chunk
  int* pmax = (int*)(xl + STAGE_MAX_HW);
  const int tid = threadIdx.x;
  const float* xg = a.x[seq];

  // hoisted: zero staging slab once (covers halo + channel pad; payload gets
  // overwritten by each chunk's staging)
  for (int i = tid; i < STAGE_HW / 8; i += 256) ((uint4*)xl)[i] = uint4{0, 0, 0, 0};

  const int wave = tid >> 6, lane = tid & 63, quad = lane >> 4, m = lane & 15;

  // hoisted: preload the 22 non-zero B fragments for this seq (once per block)
  const bfrag* wp = a.Wpack + (size_t)(seq * 5 * 7) * 64 + lane;
  bfrag Bf[22];
  {
    int bi = 0;
#pragma unroll
    for (int i = 0; i < SN0; ++i) Bf[bi++] = wp[(0 * 7 + SLO0 + i) * 64];
#pragma unroll
    for (int i = 0; i < SN1; ++i) Bf[bi++] = wp[(1 * 7 + SLO1 + i) * 64];
#pragma unroll
    for (int i = 0; i < SN2; ++i) Bf[bi++] = wp[(2 * 7 + SLO2 + i) * 64];
#pragma unroll
    for (int i = 0; i < SN3; ++i) Bf[bi++] = wp[(3 * 7 + SLO3 + i) * 64];
#pragma unroll
    for (int i = 0; i < SN4; ++i) Bf[bi++] = wp[(4 * 7 + SLO4 + i) * 64];
  }
  // Bf base offsets per nt: {0, 1, 4, 9, 15}

  __syncthreads();   // slab zeroed

#pragma unroll 1
  for (int ch = 0; ch < 2; ++ch) {
    const int c0 = b0 + ch * 32;

    // zero pmax (this chunk) + stage payload -> bf16 [b][pos=xi+4][c]
    for (int i = tid; i < 32 * PMAX_STRIDE / 4; i += 256) ((uint4*)pmax)[i] = uint4{0, 0, 0, 0};
    for (int j = tid; j < NJ; j += 256) {
      int s = j / (10 * NC), r2 = j - s * (10 * NC);
      int cp = r2 / NC, ci = r2 - cp * NC;
      int xi0 = (4 * ci > L - 4) ? (L - 4) : 4 * ci;   // overlapping tail chunk
      const float* rowA = xg + ((size_t)(c0 + s) * 20 + 2 * cp) * L + xi0;
      f32x4u fa = *(const f32x4u*)rowA;
      f32x4u fb = *(const f32x4u*)(rowA + L);
      unsigned short* dst = xl + s * SHW + (4 + xi0) * 24 + 2 * cp;
#pragma unroll
      for (int jj = 0; jj < 4; ++jj) {
        unsigned int pk;
        asm("v_cvt_pk_bf16_f32 %0, %1, %2" : "=v"(pk) : "v"(fa[jj]), "v"(fb[jj]));
        *(unsigned int*)(dst + jj * 24) = pk;   // 4B-aligned: SHW even, 2cp even
      }
    }
    __syncthreads();   // chunk staged

    // compute the two 16-sample M-tiles (positions round-robin over waves)
#pragma unroll
    for (int mt = 0; mt < 2; ++mt) {
      f32x4 vmax[5];
#pragma unroll
      for (int g = 0; g < 5; ++g) vmax[g] = f32x4{0.f, 0.f, 0.f, 0.f};  // relu folded
      for (int l = wave; l < L; l += 4) {
        const unsigned short* arow = &xl[(mt * 16 + m) * SHW + l * 24 + quad * 8];
        f32x4 acc[5];
#pragma unroll
        for (int g = 0; g < 5; ++g) acc[g] = f32x4{0.f, 0.f, 0.f, 0.f};
        tile_mfma(arow, Bf, acc);
#pragma unroll
        for (int g = 0; g < 5; ++g) {
#pragma unroll
          for (int r4 = 0; r4 < 4; ++r4) vmax[g][r4] = fmaxf(vmax[g][r4], acc[g][r4]);
        }
      }
      // merge waves' running maxima: C row = quad*4+r4 = sample, col m = filter
#pragma unroll
      for (int g = 0; g < 5; ++g) {
#pragma unroll
        for (int r4 = 0; r4 < 4; ++r4)
          atomicMax(&pmax[(mt * 16 + quad * 4 + r4) * PMAX_STRIDE + g * 16 + m],
                    __float_as_int(vmax[g][r4]));
      }
    }
    __syncthreads();   // pmax complete

    // store: 32 samples x 10 chunks of 8 consecutive k -> one 16B store each
    for (int r = tid; r < 320; r += 256) {
      int s = r / 10, c = r - (r / 10) * 10;
      int k0 = seq * 80 + c * 8;               // multiple of 8
      bfrag outv;
#pragma unroll
      for (int j = 0; j < 8; ++j)
        outv[j] = (short)f2bf(__int_as_float(pmax[s * PMAX_STRIDE + c * 8 + j]));
      int step = k0 >> 5, q = (k0 >> 3) & 3;
      int b = c0 + s;
      *(bfrag*)(a.feats + ((size_t)(b >> 4) * 18 + step) * 512 + (size_t)(q * 16 + (b & 15)) * 8) = outv;
    }
    if (ch == 0) __syncthreads();   // protect pmax reads from next chunk's zero
  }
}

__global__ __launch_bounds__(256, 3) void conv_kernel(ConvArgs a) {
  __shared__ __align__(16) unsigned short xl[XL_HW];   // 53248 B -> 3 blocks/CU
  const int bid = blockIdx.x;
  const int seq = bid % 7;           // interleave seqs across the grid
  const int b0 = (bid / 7) * 64;
  switch (seq) {
    case 0: conv_body<12>(xl, a, 0, b0); break;
    case 1: conv_body< 7>(xl, a, 1, b0); break;
    case 2: conv_body< 8>(xl, a, 2, b0); break;
    case 3: conv_body<16>(xl, a, 3, b0); break;
    case 4: conv_body< 6>(xl, a, 4, b0); break;
    case 5: conv_body< 7>(xl, a, 5, b0); break;
    default: conv_body<18>(xl, a, 6, b0); break;
  }
}

// ---------------- MLP: feats(packed) -> sigmoid(@lin1^T+b1) -> @lin2^T+b2 ----------------
struct MlpArgs {
  const bfrag* feats;      // packed A-frag layout
  const bfrag* lin1pack;
  const float* lin1_b;
  const float* lin2_w;
  const float* lin2_b;
  float* out;
};

__global__ __launch_bounds__(256, 4) void mlp_kernel(MlpArgs a) {
  __shared__ float h[16 * 68];
  __shared__ float w2[64];
  const int tid = threadIdx.x;
  const int b0 = blockIdx.x * 16;
  if (tid < 64) w2[tid] = a.lin2_w[tid];
  const int wave = tid >> 6, lane = tid & 63, quad = lane >> 4, m = lane & 15;
  const int nt = wave;                     // one n-tile per wave
  bfrag Bf[18];
#pragma unroll
  for (int s = 0; s < 18; ++s) Bf[s] = a.lin1pack[(nt * 18 + s) * 64 + lane];
  const bfrag* ap = a.feats + (size_t)blockIdx.x * 18 * 64 + lane;  // coalesced 16B/lane
  f32x4 acc = {0.f, 0.f, 0.f, 0.f};
#pragma unroll
  for (int s = 0; s < 18; ++s)
    acc = __builtin_amdgcn_mfma_f32_16x16x32_bf16(ap[s * 64], Bf[s], acc, 0, 0, 0);
  int n = nt * 16 + m;
  float bias = a.lin1_b[n];
#pragma unroll
  for (int r = 0; r < 4; ++r) {
    float pre = acc[r] + bias;
    h[(quad * 4 + r) * 68 + n] = 1.f / (1.f + __expf(-pre));
  }
  __syncthreads();
  int bl = tid >> 4, q = tid & 15;         // 16 threads per sample, 4 h each
  const float* hr = &h[bl * 68 + q * 4];
  float s = hr[0] * w2[q * 4] + hr[1] * w2[q * 4 + 1] + hr[2] * w2[q * 4 + 2] + hr[3] * w2[q * 4 + 3];
  s += __shfl_xor(s, 1);
  s += __shfl_xor(s, 2);
  s += __shfl_xor(s, 4);
  s += __shfl_xor(s, 8);
  if (q == 0) a.out[b0 + bl] = s + a.lin2_b[0];
}

// ---------------- launch ----------------
extern "C" void kernel_launch(void* const* d_in, const int* in_sizes, int n_in,
                              void* d_out, int out_size, void* d_ws, size_t ws_size,
                              hipStream_t stream) {
  (void)in_sizes; (void)n_in; (void)out_size; (void)ws_size;
  char* ws = (char*)d_ws;
  bfrag* Wpack = (bfrag*)(ws + 0);                 // 15680*16 = 250,880 B
  bfrag* lin1pack = (bfrag*)(ws + 262144);         // 4608*16  =  73,728 B
  unsigned short* feats = (unsigned short*)(ws + 393216);  // 1024*18*64*16 = 18.87 MB

  PrepArgs pa;
  for (int j = 0; j < 5; ++j) pa.Wk[j] = (const float*)d_in[7 + j];
  pa.lin1_w = (const float*)d_in[12];
  pa.Wpack = Wpack;
  pa.lin1pack = lin1pack;
  prep_kernel<<<80, 256, 0, stream>>>(pa);

  ConvArgs ca;
  for (int i = 0; i < NSEQ; ++i) ca.x[i] = (const float*)d_in[i];
  ca.Wpack = Wpack;
  ca.feats = feats;
  // 1792 blocks: 256 per seq (64 samples = 2 chunks of 32), seqs interleaved by bid%7
  conv_kernel<<<1792, 256, 0, stream>>>(ca);

  MlpArgs ma;
  ma.feats = (const bfrag*)feats;
  ma.lin1pack = lin1pack;
  ma.lin1_b = (const float*)d_in[13];
  ma.lin2_w = (const float*)d_in[14];
  ma.lin2_b = (const float*)d_in[15];
  ma.out = (float*)d_out;
  mlp_kernel<<<1024, 256, 0, stream>>>(ma);
}

// Round 8
// 180.026 us; speedup vs baseline: 1.0227x; 1.0227x over previous
//
#include <hip/hip_runtime.h>
#include <stdint.h>
#include <stddef.h>

typedef short bfrag __attribute__((ext_vector_type(8)));
typedef float f32x4 __attribute__((ext_vector_type(4)));
typedef float f32x4u __attribute__((ext_vector_type(4), aligned(4)));  // rows are only 4B-aligned

#define NSEQ 7
// feats packed in MFMA A-fragment order: [btile(1024)][step(18)][lane(64)][j(8)] bf16
// value = feat[btile*16 + (lane&15)][k], k = step*32 + (lane>>4)*8 + j

__constant__ int c_ks[5] = {1, 3, 5, 7, 9};

// per-ksize active MFMA K-steps (B is exactly zero outside): s in [lo, lo+n)
#define SLO0 3
#define SLO1 2
#define SLO2 1
#define SLO3 0
#define SLO4 0
#define SN0 1
#define SN1 3
#define SN2 5
#define SN3 6
#define SN4 7

// LDS layout (halfwords): staging [32][SHW] bf16 (SHW padded to ==24 mod 64);
// max SHW = 664 (L=18) -> 21248 hw staging. pmax int[32][84] above: stride 84
// (not 80) so the 4-quad atomicMax merge is a free 2-way bank split instead of
// 4-way (336*q == 16q mod 32 spreads quads; 320*q == 0 collided them; r7 measured
// -29% conflicts/chunk from this). Total 53248 B -> 3 blocks/CU (159744<=163840).
// Block structure is r4's EXACTLY (32 samples, 3584 blocks): r6's explicit
// pipeline (-13%) and r7's 2-chunk blocks (-24%) both regressed — inter-block
// phase overlap at 3 blocks/CU is the pipeline; don't lengthen the serial path.
#define STAGE_MAX_HW 21248
#define PMAX_STRIDE 84
#define XL_HW (STAGE_MAX_HW + 32 * PMAX_STRIDE * 2)   // 26624 hw = 53248 B

static __device__ __forceinline__ unsigned short f2bf(float f) {
  unsigned int u = __float_as_uint(f);
  u += 0x7FFFu + ((u >> 16) & 1u);   // RNE
  return (unsigned short)(u >> 16);
}

// ---------------- prep: pack conv weights + lin1 into B-fragment layout ----------
struct PrepArgs {
  const float* Wk[5];
  const float* lin1_w;
  bfrag* Wpack;
  bfrag* lin1pack;
};

__global__ __launch_bounds__(256) void prep_kernel(PrepArgs a) {
  int tid = blockIdx.x * 256 + threadIdx.x;
  const int NW = NSEQ * 5 * 7 * 64;
  if (tid < NW) {
    int lane = tid & 63, rest = tid >> 6;
    int step = rest % 7, nt = (rest / 7) % 5, seq = rest / 35;
    int quad = lane >> 4, f = lane & 15;
    int ks = c_ks[nt], off = (9 - ks) >> 1;
    const float* W = a.Wk[nt];
    bfrag s;
#pragma unroll
    for (int j = 0; j < 8; ++j) {
      int k = step * 32 + quad * 8 + j;
      int t = k / 24, c = k % 24;
      int tap = t - off;
      float val = 0.f;
      if (c < 20 && tap >= 0 && tap < ks)
        val = W[((seq * 16 + f) * 20 + c) * ks + tap] * 0.2f;  // fold /5
      s[j] = (short)f2bf(val);
    }
    a.Wpack[tid] = s;
  } else if (tid < NW + 4 * 18 * 64) {
    int t2 = tid - NW;
    int lane = t2 & 63, rest = t2 >> 6;
    int step = rest % 18, nt = rest / 18;
    int quad = lane >> 4, col = lane & 15;
    int n = nt * 16 + col;
    bfrag s;
#pragma unroll
    for (int j = 0; j < 8; ++j) {
      int k = step * 32 + quad * 8 + j;
      float val = (k < 560) ? a.lin1_w[n * 560 + k] : 0.f;  // zero rows k>=560 make feats pad inert
      s[j] = (short)f2bf(val);
    }
    a.lin1pack[t2] = s;
  }
}

// ---------------- conv+relu+gmax: sample-tile MFMA, register max over positions ----
struct ConvArgs {
  const float* x[NSEQ];
  const bfrag* Wpack;
  unsigned short* feats;   // packed A-frag layout, see top
};

template <int SLO, int SN>
static __device__ __forceinline__ void mfma_group(f32x4& acc, int s, const bfrag& Af,
                                                  const bfrag* BfBase) {
  if (s >= SLO && s < SLO + SN)
    acc = __builtin_amdgcn_mfma_f32_16x16x32_bf16(Af, BfBase[s - SLO], acc, 0, 0, 0);
}

// One 16-sample MFMA tile over all 5 filter groups. arow = A base (includes quad*8).
static __device__ __forceinline__ void tile_mfma(const unsigned short* arow, const bfrag* Bf,
                                                 f32x4 acc[5]) {
#pragma unroll
  for (int s = 0; s < 7; ++s) {
    bfrag Af = *(const bfrag*)(arow + s * 32);
    mfma_group<SLO0, SN0>(acc[0], s, Af, Bf + 0);
    mfma_group<SLO1, SN1>(acc[1], s, Af, Bf + 1);
    mfma_group<SLO2, SN2>(acc[2], s, Af, Bf + 4);
    mfma_group<SLO3, SN3>(acc[3], s, Af, Bf + 9);
    acc[4] = __builtin_amdgcn_mfma_f32_16x16x32_bf16(Af, Bf[15 + s], acc[4], 0, 0, 0);
  }
}

// Block = 32 samples (2 M-tiles of 16). Zero phase writes ONLY the pad regions
// (leading/trailing rows + c20..23 column); payload is fully overwritten by
// staging, and pad-zeros + staging touch disjoint addresses -> one shared
// barrier (saves a syncthreads + ~60% of zero writes vs full-slab zero).
// The inter-sample alignment pad [SHW0,SHW) is never read (max A-read end
// 24L+208 < SHW0=24L+216) -> not zeroed at all.
// Live set: Bf 88 + acc 20 + vmax 20 + addr ~12 -> needs 3-waves/EU VGPR budget;
// (256,4)=128 caused scratch spills in r2.
template <int L>
__device__ __forceinline__ void conv_body(unsigned short* xl, const ConvArgs& a,
                                          const int seq, const int b0) {
  constexpr int Pv = L + 9;                 // 4 leading pad + L + 5 trailing pad
  constexpr int SHW0 = Pv * 24;
  constexpr int SHW = SHW0 + ((24 - (SHW0 & 63)) & 63);   // == 24 mod 64 halfwords
  constexpr int NC = (L + 3) / 4;           // overlapping float4 chunks per row
  constexpr int NJ = 320 * NC;              // staging jobs (32 samples)
  int* pmax = (int*)(xl + STAGE_MAX_HW);
  const int tid = threadIdx.x;
  const float* xg = a.x[seq];

  // zero pmax (32*84 ints = 672 uint4)
  for (int i = tid; i < 672; i += 256) ((uint4*)pmax)[i] = uint4{0, 0, 0, 0};
  // zero pad rows: pos 0..3 and L+4..L+8, 9 rows x 48B per sample
  for (int r = tid; r < 32 * 9; r += 256) {
    int s = r / 9, rw = r - (r / 9) * 9;
    int pos = rw < 4 ? rw : L + rw;         // rw 4..8 -> pos L+4..L+8
    uint4* p = (uint4*)(xl + s * SHW + pos * 24);
    p[0] = uint4{0, 0, 0, 0}; p[1] = uint4{0, 0, 0, 0}; p[2] = uint4{0, 0, 0, 0};
  }
  // zero c-pad (hw 20..23) of payload rows pos 4..L+3 (8B aligned: SHW even)
  for (int r = tid; r < 32 * L; r += 256) {
    int s = r / L, pp = r - (r / L) * L;
    *(uint2*)(xl + s * SHW + (4 + pp) * 24 + 20) = uint2{0, 0};
  }

  // stage payload -> bf16 [b][pos=xi+4][c]: job = (sample, channel-pair, chunk);
  // rows 2cp/2cp+1 contiguous in global; HW packed cvt + b32 writes.
  for (int j = tid; j < NJ; j += 256) {
    int s = j / (10 * NC), r2 = j - s * (10 * NC);
    int cp = r2 / NC, ci = r2 - cp * NC;
    int xi0 = (4 * ci > L - 4) ? (L - 4) : 4 * ci;   // overlapping tail chunk
    const float* rowA = xg + ((size_t)(b0 + s) * 20 + 2 * cp) * L + xi0;
    f32x4u fa = *(const f32x4u*)rowA;
    f32x4u fb = *(const f32x4u*)(rowA + L);
    unsigned short* dst = xl + s * SHW + (4 + xi0) * 24 + 2 * cp;
#pragma unroll
    for (int jj = 0; jj < 4; ++jj) {
      unsigned int pk;
      asm("v_cvt_pk_bf16_f32 %0, %1, %2" : "=v"(pk) : "v"(fa[jj]), "v"(fb[jj]));
      *(unsigned int*)(dst + jj * 24) = pk;   // 4B-aligned: SHW even, 2cp even
    }
  }

  const int wave = tid >> 6, lane = tid & 63, quad = lane >> 4, m = lane & 15;

  // preload the 22 non-zero B fragments for this seq (global, overlaps staging)
  const bfrag* wp = a.Wpack + (size_t)(seq * 5 * 7) * 64 + lane;
  bfrag Bf[22];
  {
    int bi = 0;
#pragma unroll
    for (int i = 0; i < SN0; ++i) Bf[bi++] = wp[(0 * 7 + SLO0 + i) * 64];
#pragma unroll
    for (int i = 0; i < SN1; ++i) Bf[bi++] = wp[(1 * 7 + SLO1 + i) * 64];
#pragma unroll
    for (int i = 0; i < SN2; ++i) Bf[bi++] = wp[(2 * 7 + SLO2 + i) * 64];
#pragma unroll
    for (int i = 0; i < SN3; ++i) Bf[bi++] = wp[(3 * 7 + SLO3 + i) * 64];
#pragma unroll
    for (int i = 0; i < SN4; ++i) Bf[bi++] = wp[(4 * 7 + SLO4 + i) * 64];
  }
  // Bf base offsets per nt: {0, 1, 4, 9, 15}

  __syncthreads();   // pads + payload staged (disjoint writes, single barrier)

  // compute the two 16-sample M-tiles (positions round-robin over waves)
#pragma unroll
  for (int mt = 0; mt < 2; ++mt) {
    f32x4 vmax[5];
#pragma unroll
    for (int g = 0; g < 5; ++g) vmax[g] = f32x4{0.f, 0.f, 0.f, 0.f};  // relu folded
    for (int l = wave; l < L; l += 4) {
      const unsigned short* arow = &xl[(mt * 16 + m) * SHW + l * 24 + quad * 8];
      f32x4 acc[5];
#pragma unroll
      for (int g = 0; g < 5; ++g) acc[g] = f32x4{0.f, 0.f, 0.f, 0.f};
      tile_mfma(arow, Bf, acc);
#pragma unroll
      for (int g = 0; g < 5; ++g) {
#pragma unroll
        for (int r4 = 0; r4 < 4; ++r4) vmax[g][r4] = fmaxf(vmax[g][r4], acc[g][r4]);
      }
    }
    // merge waves' running maxima: C row = quad*4+r4 = sample, col m = filter
#pragma unroll
    for (int g = 0; g < 5; ++g) {
#pragma unroll
      for (int r4 = 0; r4 < 4; ++r4)
        atomicMax(&pmax[(mt * 16 + quad * 4 + r4) * PMAX_STRIDE + g * 16 + m],
                  __float_as_int(vmax[g][r4]));
    }
  }
  __syncthreads();   // pmax complete

  // store: 32 samples x 10 chunks of 8 consecutive k -> one 16B store each
  for (int r = tid; r < 320; r += 256) {
    int s = r / 10, c = r - (r / 10) * 10;
    int k0 = seq * 80 + c * 8;               // multiple of 8
    bfrag outv;
#pragma unroll
    for (int j = 0; j < 8; ++j)
      outv[j] = (short)f2bf(__int_as_float(pmax[s * PMAX_STRIDE + c * 8 + j]));
    int step = k0 >> 5, q = (k0 >> 3) & 3;
    int b = b0 + s;
    *(bfrag*)(a.feats + ((size_t)(b >> 4) * 18 + step) * 512 + (size_t)(q * 16 + (b & 15)) * 8) = outv;
  }
}

__global__ __launch_bounds__(256, 3) void conv_kernel(ConvArgs a) {
  __shared__ __align__(16) unsigned short xl[XL_HW];   // 53248 B -> 3 blocks/CU
  const int bid = blockIdx.x;
  const int seq = bid % 7;           // interleave seqs across the grid
  const int b0 = (bid / 7) * 32;
  switch (seq) {
    case 0: conv_body<12>(xl, a, 0, b0); break;
    case 1: conv_body< 7>(xl, a, 1, b0); break;
    case 2: conv_body< 8>(xl, a, 2, b0); break;
    case 3: conv_body<16>(xl, a, 3, b0); break;
    case 4: conv_body< 6>(xl, a, 4, b0); break;
    case 5: conv_body< 7>(xl, a, 5, b0); break;
    default: conv_body<18>(xl, a, 6, b0); break;
  }
}

// ---------------- MLP: feats(packed) -> sigmoid(@lin1^T+b1) -> @lin2^T+b2 ----------------
struct MlpArgs {
  const bfrag* feats;      // packed A-frag layout
  const bfrag* lin1pack;
  const float* lin1_b;
  const float* lin2_w;
  const float* lin2_b;
  float* out;
};

__global__ __launch_bounds__(256, 4) void mlp_kernel(MlpArgs a) {
  __shared__ float h[16 * 68];
  __shared__ float w2[64];
  const int tid = threadIdx.x;
  const int b0 = blockIdx.x * 16;
  if (tid < 64) w2[tid] = a.lin2_w[tid];
  const int wave = tid >> 6, lane = tid & 63, quad = lane >> 4, m = lane & 15;
  const int nt = wave;                     // one n-tile per wave
  bfrag Bf[18];
#pragma unroll
  for (int s = 0; s < 18; ++s) Bf[s] = a.lin1pack[(nt * 18 + s) * 64 + lane];
  const bfrag* ap = a.feats + (size_t)blockIdx.x * 18 * 64 + lane;  // coalesced 16B/lane
  f32x4 acc = {0.f, 0.f, 0.f, 0.f};
#pragma unroll
  for (int s = 0; s < 18; ++s)
    acc = __builtin_amdgcn_mfma_f32_16x16x32_bf16(ap[s * 64], Bf[s], acc, 0, 0, 0);
  int n = nt * 16 + m;
  float bias = a.lin1_b[n];
#pragma unroll
  for (int r = 0; r < 4; ++r) {
    float pre = acc[r] + bias;
    h[(quad * 4 + r) * 68 + n] = 1.f / (1.f + __expf(-pre));
  }
  __syncthreads();
  int bl = tid >> 4, q = tid & 15;         // 16 threads per sample, 4 h each
  const float* hr = &h[bl * 68 + q * 4];
  float s = hr[0] * w2[q * 4] + hr[1] * w2[q * 4 + 1] + hr[2] * w2[q * 4 + 2] + hr[3] * w2[q * 4 + 3];
  s += __shfl_xor(s, 1);
  s += __shfl_xor(s, 2);
  s += __shfl_xor(s, 4);
  s += __shfl_xor(s, 8);
  if (q == 0) a.out[b0 + bl] = s + a.lin2_b[0];
}

// ---------------- launch ----------------
extern "C" void kernel_launch(void* const* d_in, const int* in_sizes, int n_in,
                              void* d_out, int out_size, void* d_ws, size_t ws_size,
                              hipStream_t stream) {
  (void)in_sizes; (void)n_in; (void)out_size; (void)ws_size;
  char* ws = (char*)d_ws;
  bfrag* Wpack = (bfrag*)(ws + 0);                 // 15680*16 = 250,880 B
  bfrag* lin1pack = (bfrag*)(ws + 262144);         // 4608*16  =  73,728 B
  unsigned short* feats = (unsigned short*)(ws + 393216);  // 1024*18*64*16 = 18.87 MB

  PrepArgs pa;
  for (int j = 0; j < 5; ++j) pa.Wk[j] = (const float*)d_in[7 + j];
  pa.lin1_w = (const float*)d_in[12];
  pa.Wpack = Wpack;
  pa.lin1pack = lin1pack;
  prep_kernel<<<80, 256, 0, stream>>>(pa);

  ConvArgs ca;
  for (int i = 0; i < NSEQ; ++i) ca.x[i] = (const float*)d_in[i];
  ca.Wpack = Wpack;
  ca.feats = feats;
  // 3584 blocks: 512 per seq (32 samples each), seqs interleaved by bid%7
  conv_kernel<<<3584, 256, 0, stream>>>(ca);

  MlpArgs ma;
  ma.feats = (const bfrag*)feats;
  ma.lin1pack = lin1pack;
  ma.lin1_b = (const float*)d_in[13];
  ma.lin2_w = (const float*)d_in[14];
  ma.lin2_b = (const float*)d_in[15];
  ma.out = (float*)d_out;
  mlp_kernel<<<1024, 256, 0, stream>>>(ma);
}

// Round 9
// 175.678 us; speedup vs baseline: 1.0480x; 1.0248x over previous
//
#include <hip/hip_runtime.h>
#include <stdint.h>
#include <stddef.h>

typedef short bfrag __attribute__((ext_vector_type(8)));
typedef float f32x4 __attribute__((ext_vector_type(4)));
typedef float f32x4u __attribute__((ext_vector_type(4), aligned(4)));  // rows are only 4B-aligned

#define NSEQ 7
// feats packed in MFMA A-fragment order: [btile(1024)][step(18)][lane(64)][j(8)] bf16
// value = feat[btile*16 + (lane&15)][k], k = step*32 + (lane>>4)*8 + j

__constant__ int c_ks[5] = {1, 3, 5, 7, 9};

// per-ksize active MFMA K-steps (B is exactly zero outside): s in [lo, lo+n)
#define SLO0 3
#define SLO1 2
#define SLO2 1
#define SLO3 0
#define SLO4 0
#define SN0 1
#define SN1 3
#define SN2 5
#define SN3 6
#define SN4 7

// LDS layout (halfwords): staging [32][SHW] bf16 (SHW padded to ==24 mod 64);
// max SHW = 664 (L=18) -> 21248 hw staging. pmax int[32][84]: stride 84 so the
// 4-quad atomicMax merge is a 2-way bank split not 4-way (336q == 16q mod 32;
// r7/r8 counters confirmed the mechanism); 84 % 4 == 0 keeps the store phase
// 16B-aligned. Total 53248 B -> 3 blocks/CU.
// Block structure = r4 EXACTLY (32 samples, 3584 blocks, dense slab zero):
// r6 explicit pipeline -13%, r7 2-chunk blocks -24%, r8 sparse-zero -11% all
// regressed — inter-block phase overlap at 3 blocks/CU is the pipeline.
#define STAGE_MAX_HW 21248
#define PMAX_STRIDE 84
#define XL_HW (STAGE_MAX_HW + 32 * PMAX_STRIDE * 2)   // 26624 hw = 53248 B

static __device__ __forceinline__ unsigned short f2bf(float f) {
  unsigned int u = __float_as_uint(f);
  u += 0x7FFFu + ((u >> 16) & 1u);   // RNE
  return (unsigned short)(u >> 16);
}

// ---------------- prep: pack conv weights + lin1 into B-fragment layout ----------
struct PrepArgs {
  const float* Wk[5];
  const float* lin1_w;
  bfrag* Wpack;
  bfrag* lin1pack;
};

__global__ __launch_bounds__(256) void prep_kernel(PrepArgs a) {
  int tid = blockIdx.x * 256 + threadIdx.x;
  const int NW = NSEQ * 5 * 7 * 64;
  if (tid < NW) {
    int lane = tid & 63, rest = tid >> 6;
    int step = rest % 7, nt = (rest / 7) % 5, seq = rest / 35;
    int quad = lane >> 4, f = lane & 15;
    int ks = c_ks[nt], off = (9 - ks) >> 1;
    const float* W = a.Wk[nt];
    bfrag s;
#pragma unroll
    for (int j = 0; j < 8; ++j) {
      int k = step * 32 + quad * 8 + j;
      int t = k / 24, c = k % 24;
      int tap = t - off;
      float val = 0.f;
      if (c < 20 && tap >= 0 && tap < ks)
        val = W[((seq * 16 + f) * 20 + c) * ks + tap] * 0.2f;  // fold /5
      s[j] = (short)f2bf(val);
    }
    a.Wpack[tid] = s;
  } else if (tid < NW + 4 * 18 * 64) {
    int t2 = tid - NW;
    int lane = t2 & 63, rest = t2 >> 6;
    int step = rest % 18, nt = rest / 18;
    int quad = lane >> 4, col = lane & 15;
    int n = nt * 16 + col;
    bfrag s;
#pragma unroll
    for (int j = 0; j < 8; ++j) {
      int k = step * 32 + quad * 8 + j;
      float val = (k < 560) ? a.lin1_w[n * 560 + k] : 0.f;  // zero rows k>=560 make feats pad inert
      s[j] = (short)f2bf(val);
    }
    a.lin1pack[t2] = s;
  }
}

// ---------------- conv+relu+gmax: sample-tile MFMA, register max over positions ----
struct ConvArgs {
  const float* x[NSEQ];
  const bfrag* Wpack;
  unsigned short* feats;   // packed A-frag layout, see top
};

template <int SLO, int SN>
static __device__ __forceinline__ void mfma_group(f32x4& acc, int s, const bfrag& Af,
                                                  const bfrag* BfBase) {
  if (s >= SLO && s < SLO + SN)
    acc = __builtin_amdgcn_mfma_f32_16x16x32_bf16(Af, BfBase[s - SLO], acc, 0, 0, 0);
}

// One 16-sample MFMA tile over all 5 filter groups. arow = A base (includes quad*8).
static __device__ __forceinline__ void tile_mfma(const unsigned short* arow, const bfrag* Bf,
                                                 f32x4 acc[5]) {
#pragma unroll
  for (int s = 0; s < 7; ++s) {
    bfrag Af = *(const bfrag*)(arow + s * 32);
    mfma_group<SLO0, SN0>(acc[0], s, Af, Bf + 0);
    mfma_group<SLO1, SN1>(acc[1], s, Af, Bf + 1);
    mfma_group<SLO2, SN2>(acc[2], s, Af, Bf + 4);
    mfma_group<SLO3, SN3>(acc[3], s, Af, Bf + 9);
    acc[4] = __builtin_amdgcn_mfma_f32_16x16x32_bf16(Af, Bf[15 + s], acc[4], 0, 0, 0);
  }
}

// Block = 32 samples (2 M-tiles of 16). Staging is TWO-PHASE: all of a thread's
// global loads issued first (held in regs, static unroll), then one drain ->
// cvt + ds_write. Collapses the 2 per-job VMEM latency stalls (~600cy each,
// the dominant unmodeled per-block cost) into 1. Held set ~80 VGPR during
// staging only; Bf loads issued after the write loop -> peak ~110 < 168
// (3-waves/EU cap; (256,4)=128 caused scratch spills in r2).
template <int L>
__device__ __forceinline__ void conv_body(unsigned short* xl, const ConvArgs& a,
                                          const int seq, const int b0) {
  constexpr int Pv = L + 9;                 // 4 leading pad + L + 5 trailing pad
  constexpr int SHW0 = Pv * 24;
  constexpr int SHW = SHW0 + ((24 - (SHW0 & 63)) & 63);   // == 24 mod 64 halfwords
  constexpr int STAGE_HW = 32 * SHW;
  constexpr int NC = (L + 3) / 4;           // overlapping float4 chunks per row
  int* pmax = (int*)(xl + STAGE_MAX_HW);
  const int tid = threadIdx.x;
  const float* xg = a.x[seq];

  // zero staging slab (dense, coalesced uint4 — r8's sparse variant regressed)
  // and pmax (32*84 ints = 672 uint4)
  for (int i = tid; i < STAGE_HW / 8; i += 256) ((uint4*)xl)[i] = uint4{0, 0, 0, 0};
  for (int i = tid; i < 672; i += 256) ((uint4*)pmax)[i] = uint4{0, 0, 0, 0};
  __syncthreads();

  // stage x -> bf16 [b][pos=xi+4][c]: 320 jobs = (sample, channel-pair);
  // rows 2cp/2cp+1 contiguous in global.
  // phase A: issue ALL loads (<=2 jobs x NC chunks x 2 rows), hold in regs
  f32x4u ra[2][NC], rb[2][NC];
#pragma unroll
  for (int t = 0; t < 2; ++t) {
    if (t == 0 || tid < 64) {               // 320 - 256 = 64 second jobs
      int j = tid + t * 256;
      int b = j / 10, cp = j - (j / 10) * 10;
      const float* rowA = xg + ((size_t)(b0 + b) * 20 + 2 * cp) * L;
#pragma unroll
      for (int ci = 0; ci < NC; ++ci) {
        int xi0 = (4 * ci > L - 4) ? (L - 4) : 4 * ci;   // overlapping tail chunk
        ra[t][ci] = *(const f32x4u*)(rowA + xi0);
        rb[t][ci] = *(const f32x4u*)(rowA + L + xi0);
      }
    }
  }
  // phase B: packed cvt + b32 LDS writes (one latency drain for all loads)
#pragma unroll
  for (int t = 0; t < 2; ++t) {
    if (t == 0 || tid < 64) {
      int j = tid + t * 256;
      int b = j / 10, cp = j - (j / 10) * 10;
      unsigned short* dstb = xl + b * SHW + 4 * 24 + 2 * cp;
#pragma unroll
      for (int ci = 0; ci < NC; ++ci) {
        int xi0 = (4 * ci > L - 4) ? (L - 4) : 4 * ci;
#pragma unroll
        for (int jj = 0; jj < 4; ++jj) {
          unsigned int pk;
          asm("v_cvt_pk_bf16_f32 %0, %1, %2" : "=v"(pk) : "v"(ra[t][ci][jj]), "v"(rb[t][ci][jj]));
          *(unsigned int*)(dstb + (xi0 + jj) * 24) = pk;   // 4B-aligned: SHW even, 2cp even
        }
      }
    }
  }

  const int wave = tid >> 6, lane = tid & 63, quad = lane >> 4, m = lane & 15;

  // preload the 22 non-zero B fragments for this seq (after the write loop so
  // the held-register peak stays bounded; latency hides under the barrier)
  const bfrag* wp = a.Wpack + (size_t)(seq * 5 * 7) * 64 + lane;
  bfrag Bf[22];
  {
    int bi = 0;
#pragma unroll
    for (int i = 0; i < SN0; ++i) Bf[bi++] = wp[(0 * 7 + SLO0 + i) * 64];
#pragma unroll
    for (int i = 0; i < SN1; ++i) Bf[bi++] = wp[(1 * 7 + SLO1 + i) * 64];
#pragma unroll
    for (int i = 0; i < SN2; ++i) Bf[bi++] = wp[(2 * 7 + SLO2 + i) * 64];
#pragma unroll
    for (int i = 0; i < SN3; ++i) Bf[bi++] = wp[(3 * 7 + SLO3 + i) * 64];
#pragma unroll
    for (int i = 0; i < SN4; ++i) Bf[bi++] = wp[(4 * 7 + SLO4 + i) * 64];
  }
  // Bf base offsets per nt: {0, 1, 4, 9, 15}

  __syncthreads();   // chunk staged

  // compute the two 16-sample M-tiles (positions round-robin over waves)
#pragma unroll
  for (int mt = 0; mt < 2; ++mt) {
    f32x4 vmax[5];
#pragma unroll
    for (int g = 0; g < 5; ++g) vmax[g] = f32x4{0.f, 0.f, 0.f, 0.f};  // relu folded
    for (int l = wave; l < L; l += 4) {
      const unsigned short* arow = &xl[(mt * 16 + m) * SHW + l * 24 + quad * 8];
      f32x4 acc[5];
#pragma unroll
      for (int g = 0; g < 5; ++g) acc[g] = f32x4{0.f, 0.f, 0.f, 0.f};
      tile_mfma(arow, Bf, acc);
#pragma unroll
      for (int g = 0; g < 5; ++g) {
#pragma unroll
        for (int r4 = 0; r4 < 4; ++r4) vmax[g][r4] = fmaxf(vmax[g][r4], acc[g][r4]);
      }
    }
    // merge waves' running maxima: C row = quad*4+r4 = sample, col m = filter
#pragma unroll
    for (int g = 0; g < 5; ++g) {
#pragma unroll
      for (int r4 = 0; r4 < 4; ++r4)
        atomicMax(&pmax[(mt * 16 + quad * 4 + r4) * PMAX_STRIDE + g * 16 + m],
                  __float_as_int(vmax[g][r4]));
    }
  }
  __syncthreads();   // pmax complete

  // store: 32 samples x 10 chunks of 8 consecutive k -> one 16B store each
  for (int r = tid; r < 320; r += 256) {
    int s = r / 10, c = r - (r / 10) * 10;
    int k0 = seq * 80 + c * 8;               // multiple of 8
    bfrag outv;
#pragma unroll
    for (int j = 0; j < 8; ++j)
      outv[j] = (short)f2bf(__int_as_float(pmax[s * PMAX_STRIDE + c * 8 + j]));
    int step = k0 >> 5, q = (k0 >> 3) & 3;
    int b = b0 + s;
    *(bfrag*)(a.feats + ((size_t)(b >> 4) * 18 + step) * 512 + (size_t)(q * 16 + (b & 15)) * 8) = outv;
  }
}

__global__ __launch_bounds__(256, 3) void conv_kernel(ConvArgs a) {
  __shared__ __align__(16) unsigned short xl[XL_HW];   // 53248 B -> 3 blocks/CU
  const int bid = blockIdx.x;
  const int seq = bid % 7;           // interleave seqs across the grid
  const int b0 = (bid / 7) * 32;
  switch (seq) {
    case 0: conv_body<12>(xl, a, 0, b0); break;
    case 1: conv_body< 7>(xl, a, 1, b0); break;
    case 2: conv_body< 8>(xl, a, 2, b0); break;
    case 3: conv_body<16>(xl, a, 3, b0); break;
    case 4: conv_body< 6>(xl, a, 4, b0); break;
    case 5: conv_body< 7>(xl, a, 5, b0); break;
    default: conv_body<18>(xl, a, 6, b0); break;
  }
}

// ---------------- MLP: feats(packed) -> sigmoid(@lin1^T+b1) -> @lin2^T+b2 ----------------
struct MlpArgs {
  const bfrag* feats;      // packed A-frag layout
  const bfrag* lin1pack;
  const float* lin1_b;
  const float* lin2_w;
  const float* lin2_b;
  float* out;
};

__global__ __launch_bounds__(256, 4) void mlp_kernel(MlpArgs a) {
  __shared__ float h[16 * 68];
  __shared__ float w2[64];
  const int tid = threadIdx.x;
  const int b0 = blockIdx.x * 16;
  if (tid < 64) w2[tid] = a.lin2_w[tid];
  const int wave = tid >> 6, lane = tid & 63, quad = lane >> 4, m = lane & 15;
  const int nt = wave;                     // one n-tile per wave
  bfrag Bf[18];
#pragma unroll
  for (int s = 0; s < 18; ++s) Bf[s] = a.lin1pack[(nt * 18 + s) * 64 + lane];
  const bfrag* ap = a.feats + (size_t)blockIdx.x * 18 * 64 + lane;  // coalesced 16B/lane
  f32x4 acc = {0.f, 0.f, 0.f, 0.f};
#pragma unroll
  for (int s = 0; s < 18; ++s)
    acc = __builtin_amdgcn_mfma_f32_16x16x32_bf16(ap[s * 64], Bf[s], acc, 0, 0, 0);
  int n = nt * 16 + m;
  float bias = a.lin1_b[n];
#pragma unroll
  for (int r = 0; r < 4; ++r) {
    float pre = acc[r] + bias;
    h[(quad * 4 + r) * 68 + n] = 1.f / (1.f + __expf(-pre));
  }
  __syncthreads();
  int bl = tid >> 4, q = tid & 15;         // 16 threads per sample, 4 h each
  const float* hr = &h[bl * 68 + q * 4];
  float s = hr[0] * w2[q * 4] + hr[1] * w2[q * 4 + 1] + hr[2] * w2[q * 4 + 2] + hr[3] * w2[q * 4 + 3];
  s += __shfl_xor(s, 1);
  s += __shfl_xor(s, 2);
  s += __shfl_xor(s, 4);
  s += __shfl_xor(s, 8);
  if (q == 0) a.out[b0 + bl] = s + a.lin2_b[0];
}

// ---------------- launch ----------------
extern "C" void kernel_launch(void* const* d_in, const int* in_sizes, int n_in,
                              void* d_out, int out_size, void* d_ws, size_t ws_size,
                              hipStream_t stream) {
  (void)in_sizes; (void)n_in; (void)out_size; (void)ws_size;
  char* ws = (char*)d_ws;
  bfrag* Wpack = (bfrag*)(ws + 0);                 // 15680*16 = 250,880 B
  bfrag* lin1pack = (bfrag*)(ws + 262144);         // 4608*16  =  73,728 B
  unsigned short* feats = (unsigned short*)(ws + 393216);  // 1024*18*64*16 = 18.87 MB

  PrepArgs pa;
  for (int j = 0; j < 5; ++j) pa.Wk[j] = (const float*)d_in[7 + j];
  pa.lin1_w = (const float*)d_in[12];
  pa.Wpack = Wpack;
  pa.lin1pack = lin1pack;
  prep_kernel<<<80, 256, 0, stream>>>(pa);

  ConvArgs ca;
  for (int i = 0; i < NSEQ; ++i) ca.x[i] = (const float*)d_in[i];
  ca.Wpack = Wpack;
  ca.feats = feats;
  // 3584 blocks: 512 per seq (32 samples each), seqs interleaved by bid%7
  conv_kernel<<<3584, 256, 0, stream>>>(ca);

  MlpArgs ma;
  ma.feats = (const bfrag*)feats;
  ma.lin1pack = lin1pack;
  ma.lin1_b = (const float*)d_in[13];
  ma.lin2_w = (const float*)d_in[14];
  ma.lin2_b = (const float*)d_in[15];
  ma.out = (float*)d_out;
  mlp_kernel<<<1024, 256, 0, stream>>>(ma);
}

// Round 10
// 171.421 us; speedup vs baseline: 1.0741x; 1.0248x over previous
//
#include <hip/hip_runtime.h>
#include <stdint.h>
#include <stddef.h>

typedef short bfrag __attribute__((ext_vector_type(8)));
typedef float f32x4 __attribute__((ext_vector_type(4)));
typedef float f32x4u __attribute__((ext_vector_type(4), aligned(4)));  // rows are only 4B-aligned

#define NSEQ 7
// feats packed in MFMA A-fragment order: [btile(1024)][step(18)][lane(64)][j(8)] bf16
// value = feat[btile*16 + (lane&15)][k], k = step*32 + (lane>>4)*8 + j

__constant__ int c_ks[5] = {1, 3, 5, 7, 9};

// per-ksize active MFMA K-steps (B is exactly zero outside): s in [lo, lo+n)
#define SLO0 3
#define SLO1 2
#define SLO2 1
#define SLO3 0
#define SLO4 0
#define SN0 1
#define SN1 3
#define SN2 5
#define SN3 6
#define SN4 7

// LDS layout (halfwords): staging [32][SHW] bf16 (SHW padded to ==24 mod 64);
// max SHW = 664 (L=18) -> 21248 hw staging. pmax int[32][84]: stride 84 so the
// 4-quad atomicMax merge is a 2-way bank split not 4-way (336q == 16q mod 32;
// conflicts 3.6M->2.48M measured r9). Total 53248 B -> 3 blocks/CU.
// Block structure = r4's (32 samples, 3584 blocks): r6 explicit pipeline -13%,
// r7 2-chunk blocks -24%, r8 sparse-zero -11% all regressed — inter-block phase
// overlap at 3 blocks/CU is the pipeline; don't lengthen the serial path.
#define STAGE_MAX_HW 21248
#define PMAX_STRIDE 84
#define XL_HW (STAGE_MAX_HW + 32 * PMAX_STRIDE * 2)   // 26624 hw = 53248 B

static __device__ __forceinline__ unsigned short f2bf(float f) {
  unsigned int u = __float_as_uint(f);
  u += 0x7FFFu + ((u >> 16) & 1u);   // RNE
  return (unsigned short)(u >> 16);
}

// ---------------- prep: pack conv weights + lin1 into B-fragment layout ----------
struct PrepArgs {
  const float* Wk[5];
  const float* lin1_w;
  bfrag* Wpack;
  bfrag* lin1pack;
};

__global__ __launch_bounds__(256) void prep_kernel(PrepArgs a) {
  int tid = blockIdx.x * 256 + threadIdx.x;
  const int NW = NSEQ * 5 * 7 * 64;
  if (tid < NW) {
    int lane = tid & 63, rest = tid >> 6;
    int step = rest % 7, nt = (rest / 7) % 5, seq = rest / 35;
    int quad = lane >> 4, f = lane & 15;
    int ks = c_ks[nt], off = (9 - ks) >> 1;
    const float* W = a.Wk[nt];
    bfrag s;
#pragma unroll
    for (int j = 0; j < 8; ++j) {
      int k = step * 32 + quad * 8 + j;
      int t = k / 24, c = k % 24;
      int tap = t - off;
      float val = 0.f;
      if (c < 20 && tap >= 0 && tap < ks)
        val = W[((seq * 16 + f) * 20 + c) * ks + tap] * 0.2f;  // fold /5
      s[j] = (short)f2bf(val);
    }
    a.Wpack[tid] = s;
  } else if (tid < NW + 4 * 18 * 64) {
    int t2 = tid - NW;
    int lane = t2 & 63, rest = t2 >> 6;
    int step = rest % 18, nt = rest / 18;
    int quad = lane >> 4, col = lane & 15;
    int n = nt * 16 + col;
    bfrag s;
#pragma unroll
    for (int j = 0; j < 8; ++j) {
      int k = step * 32 + quad * 8 + j;
      float val = (k < 560) ? a.lin1_w[n * 560 + k] : 0.f;  // zero rows k>=560 make feats pad inert
      s[j] = (short)f2bf(val);
    }
    a.lin1pack[t2] = s;
  }
}

// ---------------- conv+relu+gmax: sample-tile MFMA, register max over positions ----
struct ConvArgs {
  const float* x[NSEQ];
  const bfrag* Wpack;
  unsigned short* feats;   // packed A-frag layout, see top
};

template <int SLO, int SN>
static __device__ __forceinline__ void mfma_group(f32x4& acc, int s, const bfrag& Af,
                                                  const bfrag* BfBase) {
  if (s >= SLO && s < SLO + SN)
    acc = __builtin_amdgcn_mfma_f32_16x16x32_bf16(Af, BfBase[s - SLO], acc, 0, 0, 0);
}

// One 16-sample MFMA tile over all 5 filter groups. arow = A base (includes quad*8).
static __device__ __forceinline__ void tile_mfma(const unsigned short* arow, const bfrag* Bf,
                                                 f32x4 acc[5]) {
#pragma unroll
  for (int s = 0; s < 7; ++s) {
    bfrag Af = *(const bfrag*)(arow + s * 32);
    mfma_group<SLO0, SN0>(acc[0], s, Af, Bf + 0);
    mfma_group<SLO1, SN1>(acc[1], s, Af, Bf + 1);
    mfma_group<SLO2, SN2>(acc[2], s, Af, Bf + 4);
    mfma_group<SLO3, SN3>(acc[3], s, Af, Bf + 9);
    acc[4] = __builtin_amdgcn_mfma_f32_16x16x32_bf16(Af, Bf[15 + s], acc[4], 0, 0, 0);
  }
}

// Block = 32 samples (2 M-tiles of 16). Staging is two-phase (issue all loads,
// one drain, cvt+write). Live peak ~110 VGPR < 168 (3-waves/EU cap; (256,4)=128
// caused scratch spills in r2).
template <int L>
__device__ __forceinline__ void conv_body(unsigned short* xl, const ConvArgs& a,
                                          const int seq, const int b0) {
  constexpr int Pv = L + 9;                 // 4 leading pad + L + 5 trailing pad
  constexpr int SHW0 = Pv * 24;
  constexpr int SHW = SHW0 + ((24 - (SHW0 & 63)) & 63);   // == 24 mod 64 halfwords
  constexpr int STAGE_HW = 32 * SHW;
  constexpr int NC = (L + 3) / 4;           // overlapping float4 chunks per row
  int* pmax = (int*)(xl + STAGE_MAX_HW);
  const int tid = threadIdx.x;
  const float* xg = a.x[seq];

  // zero staging slab (dense, coalesced uint4 — r8's sparse variant regressed)
  // and pmax (32*84 ints = 672 uint4)
  for (int i = tid; i < STAGE_HW / 8; i += 256) ((uint4*)xl)[i] = uint4{0, 0, 0, 0};
  for (int i = tid; i < 672; i += 256) ((uint4*)pmax)[i] = uint4{0, 0, 0, 0};
  __syncthreads();

  // stage x -> bf16 [b][pos=xi+4][c]: 320 jobs = (sample, channel-pair);
  // rows 2cp/2cp+1 contiguous in global.
  // phase A: issue ALL loads (<=2 jobs x NC chunks x 2 rows), hold in regs
  f32x4u ra[2][NC], rb[2][NC];
#pragma unroll
  for (int t = 0; t < 2; ++t) {
    if (t == 0 || tid < 64) {               // 320 - 256 = 64 second jobs
      int j = tid + t * 256;
      int b = j / 10, cp = j - (j / 10) * 10;
      const float* rowA = xg + ((size_t)(b0 + b) * 20 + 2 * cp) * L;
#pragma unroll
      for (int ci = 0; ci < NC; ++ci) {
        int xi0 = (4 * ci > L - 4) ? (L - 4) : 4 * ci;   // overlapping tail chunk
        ra[t][ci] = *(const f32x4u*)(rowA + xi0);
        rb[t][ci] = *(const f32x4u*)(rowA + L + xi0);
      }
    }
  }
  // phase B: packed cvt + b32 LDS writes (one latency drain for all loads)
#pragma unroll
  for (int t = 0; t < 2; ++t) {
    if (t == 0 || tid < 64) {
      int j = tid + t * 256;
      int b = j / 10, cp = j - (j / 10) * 10;
      unsigned short* dstb = xl + b * SHW + 4 * 24 + 2 * cp;
#pragma unroll
      for (int ci = 0; ci < NC; ++ci) {
        int xi0 = (4 * ci > L - 4) ? (L - 4) : 4 * ci;
#pragma unroll
        for (int jj = 0; jj < 4; ++jj) {
          unsigned int pk;
          asm("v_cvt_pk_bf16_f32 %0, %1, %2" : "=v"(pk) : "v"(ra[t][ci][jj]), "v"(rb[t][ci][jj]));
          *(unsigned int*)(dstb + (xi0 + jj) * 24) = pk;   // 4B-aligned: SHW even, 2cp even
        }
      }
    }
  }

  const int wave = tid >> 6, lane = tid & 63, quad = lane >> 4, m = lane & 15;

  // preload the 22 non-zero B fragments for this seq (after the write loop so
  // the held-register peak stays bounded; latency hides under the barrier)
  const bfrag* wp = a.Wpack + (size_t)(seq * 5 * 7) * 64 + lane;
  bfrag Bf[22];
  {
    int bi = 0;
#pragma unroll
    for (int i = 0; i < SN0; ++i) Bf[bi++] = wp[(0 * 7 + SLO0 + i) * 64];
#pragma unroll
    for (int i = 0; i < SN1; ++i) Bf[bi++] = wp[(1 * 7 + SLO1 + i) * 64];
#pragma unroll
    for (int i = 0; i < SN2; ++i) Bf[bi++] = wp[(2 * 7 + SLO2 + i) * 64];
#pragma unroll
    for (int i = 0; i < SN3; ++i) Bf[bi++] = wp[(3 * 7 + SLO3 + i) * 64];
#pragma unroll
    for (int i = 0; i < SN4; ++i) Bf[bi++] = wp[(4 * 7 + SLO4 + i) * 64];
  }
  // Bf base offsets per nt: {0, 1, 4, 9, 15}

  __syncthreads();   // chunk staged

  // compute the two 16-sample M-tiles (positions round-robin over waves)
#pragma unroll
  for (int mt = 0; mt < 2; ++mt) {
    f32x4 vmax[5];
#pragma unroll
    for (int g = 0; g < 5; ++g) vmax[g] = f32x4{0.f, 0.f, 0.f, 0.f};  // relu folded
    for (int l = wave; l < L; l += 4) {
      const unsigned short* arow = &xl[(mt * 16 + m) * SHW + l * 24 + quad * 8];
      f32x4 acc[5];
#pragma unroll
      for (int g = 0; g < 5; ++g) acc[g] = f32x4{0.f, 0.f, 0.f, 0.f};
      tile_mfma(arow, Bf, acc);
#pragma unroll
      for (int g = 0; g < 5; ++g) {
#pragma unroll
        for (int r4 = 0; r4 < 4; ++r4) vmax[g][r4] = fmaxf(vmax[g][r4], acc[g][r4]);
      }
    }
    // merge waves' running maxima: C row = quad*4+r4 = sample, col m = filter
#pragma unroll
    for (int g = 0; g < 5; ++g) {
#pragma unroll
      for (int r4 = 0; r4 < 4; ++r4)
        atomicMax(&pmax[(mt * 16 + quad * 4 + r4) * PMAX_STRIDE + g * 16 + m],
                  __float_as_int(vmax[g][r4]));
    }
  }
  __syncthreads();   // pmax complete

  // store: 32 samples x 10 chunks of 8 consecutive k -> one 16B store each
  for (int r = tid; r < 320; r += 256) {
    int s = r / 10, c = r - (r / 10) * 10;
    int k0 = seq * 80 + c * 8;               // multiple of 8
    bfrag outv;
#pragma unroll
    for (int j = 0; j < 8; ++j)
      outv[j] = (short)f2bf(__int_as_float(pmax[s * PMAX_STRIDE + c * 8 + j]));
    int step = k0 >> 5, q = (k0 >> 3) & 3;
    int b = b0 + s;
    *(bfrag*)(a.feats + ((size_t)(b >> 4) * 18 + step) * 512 + (size_t)(q * 16 + (b & 15)) * 8) = outv;
  }
}

__global__ __launch_bounds__(256, 3) void conv_kernel(ConvArgs a) {
  __shared__ __align__(16) unsigned short xl[XL_HW];   // 53248 B -> 3 blocks/CU
  const int bid = blockIdx.x;
  // grouped + LPT-ordered: 512 contiguous blocks per seq, longest L first.
  // (a) dispatch tail ends on the SHORTEST blocks (L=6) instead of random;
  // (b) a CU's 3 resident blocks share one conv_body specialization (i-cache).
  const int grp = bid >> 9, b0 = (bid & 511) * 32;
  switch (grp) {
    case 0: conv_body<18>(xl, a, 6, b0); break;   // L=18
    case 1: conv_body<16>(xl, a, 3, b0); break;   // L=16
    case 2: conv_body<12>(xl, a, 0, b0); break;   // L=12
    case 3: conv_body< 8>(xl, a, 2, b0); break;   // L=8
    case 4: conv_body< 7>(xl, a, 1, b0); break;   // L=7
    case 5: conv_body< 7>(xl, a, 5, b0); break;   // L=7
    default: conv_body< 6>(xl, a, 4, b0); break;  // L=6
  }
}

// ---------------- MLP: feats(packed) -> sigmoid(@lin1^T+b1) -> @lin2^T+b2 ----------------
// 32 samples/block (2 feats btiles): halves the per-block 73.7 KB lin1pack
// re-read (was 1024 blocks x 73.7 KB = 75 MB of L2 traffic) and gives each wave
// two independent MFMA chains for latency hiding.
struct MlpArgs {
  const bfrag* feats;      // packed A-frag layout
  const bfrag* lin1pack;
  const float* lin1_b;
  const float* lin2_w;
  const float* lin2_b;
  float* out;
};

__global__ __launch_bounds__(256, 4) void mlp_kernel(MlpArgs a) {
  __shared__ float h[32 * 68];
  __shared__ float w2[64];
  const int tid = threadIdx.x;
  const int b0 = blockIdx.x * 32;
  if (tid < 64) w2[tid] = a.lin2_w[tid];
  const int wave = tid >> 6, lane = tid & 63, quad = lane >> 4, m = lane & 15;
  const int nt = wave;                     // one n-tile per wave
  bfrag Bf[18];
#pragma unroll
  for (int s = 0; s < 18; ++s) Bf[s] = a.lin1pack[(nt * 18 + s) * 64 + lane];
  const bfrag* ap0 = a.feats + (size_t)(2 * blockIdx.x) * 18 * 64 + lane;  // btile 2i
  const bfrag* ap1 = ap0 + 18 * 64;                                        // btile 2i+1
  f32x4 acc0 = {0.f, 0.f, 0.f, 0.f}, acc1 = {0.f, 0.f, 0.f, 0.f};
#pragma unroll
  for (int s = 0; s < 18; ++s) {
    acc0 = __builtin_amdgcn_mfma_f32_16x16x32_bf16(ap0[s * 64], Bf[s], acc0, 0, 0, 0);
    acc1 = __builtin_amdgcn_mfma_f32_16x16x32_bf16(ap1[s * 64], Bf[s], acc1, 0, 0, 0);
  }
  int n = nt * 16 + m;
  float bias = a.lin1_b[n];
#pragma unroll
  for (int r = 0; r < 4; ++r) {
    float p0 = acc0[r] + bias, p1 = acc1[r] + bias;
    h[(quad * 4 + r) * 68 + n] = 1.f / (1.f + __expf(-p0));
    h[(16 + quad * 4 + r) * 68 + n] = 1.f / (1.f + __expf(-p1));
  }
  __syncthreads();
  int q = tid & 15;                        // 16 threads per sample, 4 h each
#pragma unroll
  for (int half = 0; half < 2; ++half) {
    int bl = (tid >> 4) + half * 16;
    const float* hr = &h[bl * 68 + q * 4];
    float s = hr[0] * w2[q * 4] + hr[1] * w2[q * 4 + 1] + hr[2] * w2[q * 4 + 2] + hr[3] * w2[q * 4 + 3];
    s += __shfl_xor(s, 1);
    s += __shfl_xor(s, 2);
    s += __shfl_xor(s, 4);
    s += __shfl_xor(s, 8);
    if (q == 0) a.out[b0 + bl] = s + a.lin2_b[0];
  }
}

// ---------------- launch ----------------
extern "C" void kernel_launch(void* const* d_in, const int* in_sizes, int n_in,
                              void* d_out, int out_size, void* d_ws, size_t ws_size,
                              hipStream_t stream) {
  (void)in_sizes; (void)n_in; (void)out_size; (void)ws_size;
  char* ws = (char*)d_ws;
  bfrag* Wpack = (bfrag*)(ws + 0);                 // 15680*16 = 250,880 B
  bfrag* lin1pack = (bfrag*)(ws + 262144);         // 4608*16  =  73,728 B
  unsigned short* feats = (unsigned short*)(ws + 393216);  // 1024*18*64*16 = 18.87 MB

  PrepArgs pa;
  for (int j = 0; j < 5; ++j) pa.Wk[j] = (const float*)d_in[7 + j];
  pa.lin1_w = (const float*)d_in[12];
  pa.Wpack = Wpack;
  pa.lin1pack = lin1pack;
  prep_kernel<<<80, 256, 0, stream>>>(pa);

  ConvArgs ca;
  for (int i = 0; i < NSEQ; ++i) ca.x[i] = (const float*)d_in[i];
  ca.Wpack = Wpack;
  ca.feats = feats;
  // 3584 blocks: 512 per seq (32 samples each), grouped by seq, longest-L first
  conv_kernel<<<3584, 256, 0, stream>>>(ca);

  MlpArgs ma;
  ma.feats = (const bfrag*)feats;
  ma.lin1pack = lin1pack;
  ma.lin1_b = (const float*)d_in[13];
  ma.lin2_w = (const float*)d_in[14];
  ma.lin2_b = (const float*)d_in[15];
  ma.out = (float*)d_out;
  mlp_kernel<<<512, 256, 0, stream>>>(ma);
}